// Round 3
// baseline (225.406 us; speedup 1.0000x reference)
//
#include <hip/hip_runtime.h>
#include <cstdint>
#include <cstddef>

// ---- problem constants ----
#define DIMC    192
#define NHEADS  6
#define HEADD   32
#define KWIN    3
#define KK2     9
#define NATT    486
#define NB      16
#define NH      56
#define NWW     56
#define HPOOL   28
#define WPOOL   28
#define NPIX    784
#define VH      58
#define VW      58
#define MROWS   (NB*NH*NWW)      // 50176
#define SCALE_A 0.17677669529663687f

using bf16x8 = __attribute__((ext_vector_type(8))) short;
using f32x4  = __attribute__((ext_vector_type(4))) float;

static __device__ __forceinline__ unsigned short f2bf(float f) {
    unsigned int u = __float_as_uint(f);
    unsigned int r = (u + 0x7fffu + ((u >> 16) & 1u)) >> 16;   // RNE
    return (unsigned short)r;
}

// =====================================================================
// WT[n][k] = bf16(W[k][n]) for Wv and Wp
// =====================================================================
__global__ __launch_bounds__(256)
void wt_convert_kernel(const float* __restrict__ Wv, const float* __restrict__ Wp,
                       unsigned short* __restrict__ WTv, unsigned short* __restrict__ WTp)
{
    int idx = blockIdx.x * 256 + threadIdx.x;        // 0..73727
    int sel = idx / 36864;
    int r   = idx - sel * 36864;
    int n   = r / DIMC;
    int k   = r - n * DIMC;
    const float* W = sel ? Wp : Wv;
    unsigned short* WT = sel ? WTp : WTv;
    WT[r] = f2bf(W[k * DIMC + n]);
}

// =====================================================================
// Zero only the 1-pixel border of vp
// =====================================================================
__global__ __launch_bounds__(256)
void vp_border_zero_kernel(float* __restrict__ vp)
{
    int idx  = blockIdx.x * 256 + threadIdx.x;
    int c    = idx % DIMC;
    int rest = idx / DIMC;          // 0..3647
    int b    = rest / 228;
    int p    = rest - b * 228;
    int hi, wi;
    if (p < 58)       { hi = 0;  wi = p; }
    else if (p < 116) { hi = 57; wi = p - 58; }
    else { int q = p - 116; hi = 1 + (q >> 1); wi = (q & 1) * 57; }
    vp[(((size_t)b * VH + hi) * VW + wi) * DIMC + c] = 0.f;
}

// =====================================================================
// MFMA GEMM: C[M x 192] = A[M x 192] (fp32) * WT^T (bf16) (+bias)
// =====================================================================
template<int MODE>
__global__ __launch_bounds__(256)
void mfma_gemm_kernel(const float* __restrict__ A, const unsigned short* __restrict__ WT,
                      const float* __restrict__ bias, float* __restrict__ C)
{
    __shared__ unsigned short As[64 * DIMC];   // 24 KB, swizzled bf16

    const int t  = threadIdx.x;
    const int l  = t & 63;
    const int w  = t >> 6;
    const int wr = w >> 1;
    const int wc = w & 1;
    const int by = blockIdx.x;

    const float* Ab = A + (size_t)by * 64 * DIMC;
#pragma unroll
    for (int i = 0; i < 12; ++i) {
        int f = i * 1024 + t * 4;
        float4 v = *(const float4*)(Ab + f);
        int row = f / DIMC;
        int k   = f - row * DIMC;
        ushort4 u;
        u.x = f2bf(v.x); u.y = f2bf(v.y); u.z = f2bf(v.z); u.w = f2bf(v.w);
        int off = (row * 384 + k * 2) ^ ((row & 7) << 4);
        *(ushort4*)((char*)As + off) = u;
    }
    __syncthreads();

    f32x4 acc[2][6];
#pragma unroll
    for (int mi = 0; mi < 2; ++mi)
#pragma unroll
        for (int ni = 0; ni < 6; ++ni) acc[mi][ni] = (f32x4)0.f;

    const int arow0 = wr * 32 + (l & 15);
    const int kb    = (l >> 4) << 4;

#pragma unroll
    for (int ks = 0; ks < 6; ++ks) {
        bf16x8 a[2], b[6];
#pragma unroll
        for (int mi = 0; mi < 2; ++mi) {
            int row = arow0 + mi * 16;
            int off = (row * 384 + ks * 64 + kb) ^ ((row & 7) << 4);
            a[mi] = *(const bf16x8*)((const char*)As + off);
        }
#pragma unroll
        for (int ni = 0; ni < 6; ++ni) {
            int n = wc * 96 + ni * 16 + (l & 15);
            b[ni] = *(const bf16x8*)(WT + (size_t)n * DIMC + ks * 32 + ((l >> 4) << 3));
        }
#pragma unroll
        for (int mi = 0; mi < 2; ++mi)
#pragma unroll
            for (int ni = 0; ni < 6; ++ni)
                acc[mi][ni] = __builtin_amdgcn_mfma_f32_16x16x32_bf16(
                    a[mi], b[ni], acc[mi][ni], 0, 0, 0);
    }

#pragma unroll
    for (int mi = 0; mi < 2; ++mi) {
#pragma unroll
        for (int r = 0; r < 4; ++r) {
            int m = by * 64 + wr * 32 + mi * 16 + ((l >> 4) << 2) + r;
            float* dst;
            if (MODE == 1) {
                dst = C + (size_t)m * DIMC;
            } else {
                int bb = m / (NH * NWW);
                int rr = m - bb * (NH * NWW);
                int hi = rr / NWW;
                int wi = rr - hi * NWW;
                dst = C + (((size_t)bb * VH + hi + 1) * VW + (wi + 1)) * DIMC;
            }
#pragma unroll
            for (int ni = 0; ni < 6; ++ni) {
                int col = wc * 96 + ni * 16 + (l & 15);
                float v = acc[mi][ni][r];
                if (MODE == 1) v += bias[col];
                dst[col] = v;
            }
        }
    }
}

// =====================================================================
// Pool (2x2 avg) + attention GEMM + softmax
// =====================================================================
__global__ __launch_bounds__(256)
void pool_attn_kernel(const float* __restrict__ x, const float* __restrict__ Wa,
                      const float* __restrict__ ba, float* __restrict__ attn)
{
    __shared__ float pool_s[8][DIMC];
    __shared__ float a_s[8][NATT + 2];

    const int t  = threadIdx.x;
    const int blk = blockIdx.x;
    const int b  = blk / 98;
    const int n0 = (blk - b * 98) * 8;

    for (int idx = t; idx < 8 * DIMC; idx += 256) {
        int pi = idx / DIMC;
        int c  = idx - pi * DIMC;
        int n  = n0 + pi;
        int hh = n / WPOOL;
        int ww = n - hh * WPOOL;
        const float* xp = x + (((size_t)(b * NH + hh * 2)) * NWW + ww * 2) * DIMC + c;
        float s = xp[0] + xp[DIMC] + xp[(size_t)NWW * DIMC] + xp[(size_t)NWW * DIMC + DIMC];
        pool_s[pi][c] = 0.25f * s;
    }
    __syncthreads();

    if (t < 243) {
        float acc0[8], acc1[8];
#pragma unroll
        for (int pi = 0; pi < 8; ++pi) { acc0[pi] = 0.f; acc1[pi] = 0.f; }
        for (int k = 0; k < DIMC; ++k) {
            float w0 = Wa[(size_t)k * NATT + t];
            float w1 = Wa[(size_t)k * NATT + t + 243];
#pragma unroll
            for (int pi = 0; pi < 8; ++pi) {
                float p = pool_s[pi][k];
                acc0[pi] = fmaf(p, w0, acc0[pi]);
                acc1[pi] = fmaf(p, w1, acc1[pi]);
            }
        }
        float b0 = ba[t], b1 = ba[t + 243];
#pragma unroll
        for (int pi = 0; pi < 8; ++pi) {
            a_s[pi][t]       = (acc0[pi] + b0) * SCALE_A;
            a_s[pi][t + 243] = (acc1[pi] + b1) * SCALE_A;
        }
    }
    __syncthreads();

    for (int row = t; row < 432; row += 256) {
        int pi   = row / 54;
        int rem  = row - pi * 54;
        int head = rem / 9;
        int pp   = rem - head * 9;
        const float* ap = &a_s[pi][head * 81 + pp * 9];
        float m = ap[0];
#pragma unroll
        for (int q = 1; q < 9; ++q) m = fmaxf(m, ap[q]);
        float e[9];
        float sum = 0.f;
#pragma unroll
        for (int q = 0; q < 9; ++q) { e[q] = __expf(ap[q] - m); sum += e[q]; }
        float inv = 1.f / sum;
        int n = n0 + pi;
        float* dst = attn + (((size_t)(b * NPIX + n) * NHEADS + head) * 81 + pp * 9);
#pragma unroll
        for (int q = 0; q < 9; ++q) dst[q] = e[q] * inv;
    }
}

// =====================================================================
// Gather, parity-specialized: NI = # valid kernel-row offsets (1 or 2),
// NJ likewise for columns. p = 2*pr + (NI-1), qc = 2*qr + (NJ-1).
// Window (hh,ww) contributes with kernel offset i = p+1-2hh, j = qc+1-2ww;
// vp rows 2hh+qi, cols 2ww+qj. All loads static & batched; borders via
// clamped address + zeroed weight (cndmask, no divergence).
// Block: 192 thr = 2 pixels (qr and qr+14) x 96 float2-channels.
// =====================================================================
template<int NI, int NJ>
__global__ __launch_bounds__(192)
void gather_kernel(const float* __restrict__ attn, const float* __restrict__ vp,
                   float* __restrict__ y)
{
    const int t    = threadIdx.x;
    const int pl   = t / 96;
    const int c2   = t - pl * 96;
    const int c    = c2 * 2;
    const int head = c2 >> 4;
    const int b    = blockIdx.z;
    const int pr   = blockIdx.y;
    const int qr   = blockIdx.x + pl * 14;
    const int p    = 2 * pr + (NI - 1);
    const int qc   = 2 * qr + (NJ - 1);

    float accx = 0.f, accy = 0.f;

#pragma unroll
    for (int wi = 0; wi < NI; ++wi) {
        const int  hh  = (NI == 1) ? pr : (wi == 0 ? pr : pr + 1);
        const bool hv  = (NI == 1) || (wi == 0) || (pr + 1 < HPOOL);
        const int  hhs = hv ? hh : (HPOOL - 1);
        const int  iof = (NI == 1) ? 1 : (wi == 0 ? 2 : 0);
#pragma unroll
        for (int wj = 0; wj < NJ; ++wj) {
            const int  ww  = (NJ == 1) ? qr : (wj == 0 ? qr : qr + 1);
            const bool wv  = (NJ == 1) || (wj == 0) || (qr + 1 < WPOOL);
            const int  wws = wv ? ww : (WPOOL - 1);
            const bool ok  = hv && wv;

            const float* ap = attn +
                (((size_t)(b * NPIX + hhs * WPOOL + wws) * NHEADS + head) * 81
                 + (iof * 3 + wj * 0 + ((NJ == 1) ? 1 : (wj == 0 ? 2 : 0))) * 9);
            float a[9];
#pragma unroll
            for (int k = 0; k < 9; ++k) a[k] = ok ? ap[k] : 0.f;

            const float* vb = vp + (((size_t)(b * VH + 2 * hhs) * VW) + 2 * wws) * DIMC + c;
            float2 v[9];
#pragma unroll
            for (int qi = 0; qi < 3; ++qi)
#pragma unroll
                for (int qj = 0; qj < 3; ++qj)
                    v[qi * 3 + qj] = *(const float2*)(vb + ((size_t)qi * VW + qj) * DIMC);

#pragma unroll
            for (int k = 0; k < 9; ++k) {
                accx = fmaf(a[k], v[k].x, accx);
                accy = fmaf(a[k], v[k].y, accy);
            }
        }
    }
    size_t pix = (size_t)b * (NH * NWW) + (size_t)p * NWW + qc;
    float2 r; r.x = accx; r.y = accy;
    *(float2*)(y + pix * DIMC + c) = r;
}

// =====================================================================
extern "C" void kernel_launch(void* const* d_in, const int* in_sizes, int n_in,
                              void* d_out, int out_size, void* d_ws, size_t ws_size,
                              hipStream_t stream)
{
    const float* x  = (const float*)d_in[0];
    const float* Wv = (const float*)d_in[1];
    const float* Wa = (const float*)d_in[2];
    const float* ba = (const float*)d_in[3];
    const float* Wp = (const float*)d_in[4];
    const float* bp = (const float*)d_in[5];
    float* out = (float*)d_out;

    const size_t vp_elems   = (size_t)NB * VH * VW * DIMC;
    const size_t attn_elems = (size_t)NB * NPIX * NATT;
    const size_t y_elems    = (size_t)MROWS * DIMC;
    float* vp   = (float*)d_ws;
    float* attn = vp + vp_elems;
    float* y    = attn + attn_elems;
    unsigned short* WTv = (unsigned short*)(y + y_elems);
    unsigned short* WTp = WTv + 36864;

    vp_border_zero_kernel<<<2736, 256, 0, stream>>>(vp);
    wt_convert_kernel<<<288, 256, 0, stream>>>(Wv, Wp, WTv, WTp);

    mfma_gemm_kernel<0><<<MROWS / 64, 256, 0, stream>>>(x, WTv, nullptr, vp);
    pool_attn_kernel<<<NB * 98, 256, 0, stream>>>(x, Wa, ba, attn);

    dim3 gg(14, 28, 16);
    gather_kernel<1, 1><<<gg, 192, 0, stream>>>(attn, vp, y);
    gather_kernel<1, 2><<<gg, 192, 0, stream>>>(attn, vp, y);
    gather_kernel<2, 1><<<gg, 192, 0, stream>>>(attn, vp, y);
    gather_kernel<2, 2><<<gg, 192, 0, stream>>>(attn, vp, y);

    mfma_gemm_kernel<1><<<MROWS / 64, 256, 0, stream>>>(y, WTp, bp, out);
}

// Round 4
// 130.271 us; speedup vs baseline: 1.7303x; 1.7303x over previous
//
#include <hip/hip_runtime.h>
#include <cstdint>
#include <cstddef>

#define DIMC    192
#define NHEADS  6
#define NATT    486
#define NB      16
#define NH      56
#define NWW     56
#define HPOOL   28
#define WPOOL   28
#define NPIX    784
#define VH      58
#define VW      58
#define MROWS   (NB*NH*NWW)      // 50176
#define MPOOL   (NB*NPIX)        // 12544
#define SCALE_A 0.17677669529663687f

using bf16x8 = __attribute__((ext_vector_type(8))) short;
using f32x4  = __attribute__((ext_vector_type(4))) float;

static __device__ __forceinline__ unsigned short f2bf(float f) {
    unsigned int u = __float_as_uint(f);
    unsigned int r = (u + 0x7fffu + ((u >> 16) & 1u)) >> 16;   // RNE
    return (unsigned short)r;
}
static __device__ __forceinline__ float bf2f(unsigned short u) {
    return __uint_as_float((unsigned int)u << 16);
}

// =====================================================================
// Weight prep: WTv/WTp[n][k] = bf16(W[k][n]); WaT[512][192] = bf16(Wa[k][n]*SCALE), rows>=486 zero
// =====================================================================
__global__ __launch_bounds__(256)
void wt_convert_kernel(const float* __restrict__ Wv, const float* __restrict__ Wp,
                       const float* __restrict__ Wa,
                       unsigned short* __restrict__ WTv, unsigned short* __restrict__ WTp,
                       unsigned short* __restrict__ WaT)
{
    int idx = blockIdx.x * 256 + threadIdx.x;        // 0..172031
    if (idx < 73728) {
        int sel = idx / 36864;
        int r   = idx - sel * 36864;
        int n   = r / DIMC;
        int k   = r - n * DIMC;
        const float* W = sel ? Wp : Wv;
        unsigned short* WT = sel ? WTp : WTv;
        WT[r] = f2bf(W[k * DIMC + n]);
    } else {
        int r = idx - 73728;                          // 0..98303
        int n = r / DIMC;
        int k = r - n * DIMC;
        WaT[r] = (n < NATT) ? f2bf(Wa[(size_t)k * NATT + n] * SCALE_A) : (unsigned short)0;
    }
}

// =====================================================================
// Zero the 1-pixel border of vp (bf16), as uint (2 channels) writes
// 16 * 228 * 96 = 350208 uints
// =====================================================================
__global__ __launch_bounds__(256)
void vp_border_zero_kernel(unsigned int* __restrict__ vpu)
{
    int idx = blockIdx.x * 256 + threadIdx.x;
    if (idx >= 350208) return;
    int cu   = idx % 96;
    int rest = idx / 96;
    int b    = rest / 228;
    int p    = rest - b * 228;
    int hi, wi;
    if (p < 58)       { hi = 0;  wi = p; }
    else if (p < 116) { hi = 57; wi = p - 58; }
    else { int q = p - 116; hi = 1 + (q >> 1); wi = (q & 1) * 57; }
    vpu[(((size_t)b * VH + hi) * VW + wi) * 96 + cu] = 0u;
}

// =====================================================================
// MFMA GEMM, BM=64, BN=192 (full), 4 waves (2x2).
// MODE 0: A fp32 (x), C bf16 scattered into padded vp
// MODE 1: A bf16 (y), C fp32 + bias -> out
// =====================================================================
template<int MODE>
__global__ __launch_bounds__(256)
void mfma_gemm_kernel(const void* __restrict__ Av, const unsigned short* __restrict__ WT,
                      const float* __restrict__ bias, void* __restrict__ Cv)
{
    __shared__ unsigned short As[64 * DIMC];   // 24 KB swizzled bf16

    const int t  = threadIdx.x;
    const int l  = t & 63;
    const int w  = t >> 6;
    const int wr = w >> 1;
    const int wc = w & 1;
    const int by = blockIdx.x;

    if (MODE == 0) {
        const float* Ab = (const float*)Av + (size_t)by * 64 * DIMC;
#pragma unroll
        for (int i = 0; i < 12; ++i) {
            int f = i * 1024 + t * 4;
            float4 v = *(const float4*)(Ab + f);
            int row = f / DIMC;
            int k   = f - row * DIMC;
            ushort4 u;
            u.x = f2bf(v.x); u.y = f2bf(v.y); u.z = f2bf(v.z); u.w = f2bf(v.w);
            int off = (row * 384 + k * 2) ^ ((row & 7) << 4);
            *(ushort4*)((char*)As + off) = u;
        }
    } else {
        const unsigned short* Ab = (const unsigned short*)Av + (size_t)by * 64 * DIMC;
#pragma unroll
        for (int i = 0; i < 6; ++i) {
            int f = i * 2048 + t * 8;
            bf16x8 v = *(const bf16x8*)(Ab + f);
            int row = f / DIMC;
            int k   = f - row * DIMC;
            int off = (row * 384 + k * 2) ^ ((row & 7) << 4);
            *(bf16x8*)((char*)As + off) = v;
        }
    }
    __syncthreads();

    f32x4 acc[2][6];
#pragma unroll
    for (int mi = 0; mi < 2; ++mi)
#pragma unroll
        for (int ni = 0; ni < 6; ++ni) acc[mi][ni] = (f32x4)0.f;

    const int arow0 = wr * 32 + (l & 15);
    const int kb    = (l >> 4) << 4;

#pragma unroll
    for (int ks = 0; ks < 6; ++ks) {
        bf16x8 a[2], b[6];
#pragma unroll
        for (int mi = 0; mi < 2; ++mi) {
            int row = arow0 + mi * 16;
            int off = (row * 384 + ks * 64 + kb) ^ ((row & 7) << 4);
            a[mi] = *(const bf16x8*)((const char*)As + off);
        }
#pragma unroll
        for (int ni = 0; ni < 6; ++ni) {
            int n = wc * 96 + ni * 16 + (l & 15);
            b[ni] = *(const bf16x8*)(WT + (size_t)n * DIMC + ks * 32 + ((l >> 4) << 3));
        }
#pragma unroll
        for (int mi = 0; mi < 2; ++mi)
#pragma unroll
            for (int ni = 0; ni < 6; ++ni)
                acc[mi][ni] = __builtin_amdgcn_mfma_f32_16x16x32_bf16(
                    a[mi], b[ni], acc[mi][ni], 0, 0, 0);
    }

#pragma unroll
    for (int mi = 0; mi < 2; ++mi) {
#pragma unroll
        for (int r = 0; r < 4; ++r) {
            int m = by * 64 + wr * 32 + mi * 16 + ((l >> 4) << 2) + r;
            if (MODE == 1) {
                float* dst = (float*)Cv + (size_t)m * DIMC;
#pragma unroll
                for (int ni = 0; ni < 6; ++ni) {
                    int col = wc * 96 + ni * 16 + (l & 15);
                    dst[col] = acc[mi][ni][r] + bias[col];
                }
            } else {
                int bb = m / (NH * NWW);
                int rr = m - bb * (NH * NWW);
                int hi = rr / NWW;
                int wi = rr - hi * NWW;
                unsigned short* dst = (unsigned short*)Cv +
                    (((size_t)bb * VH + hi + 1) * VW + (wi + 1)) * DIMC;
#pragma unroll
                for (int ni = 0; ni < 6; ++ni) {
                    int col = wc * 96 + ni * 16 + (l & 15);
                    dst[col] = f2bf(acc[mi][ni][r]);
                }
            }
        }
    }
}

// =====================================================================
// Fused pool (2x2 avg, in A-staging) + MFMA GEMM (M=12544, N=512pad, K=192)
// + bias/scale + softmax (16-row LDS chunks) -> attn[m][486] fp32
// 512 threads (8 waves, 2 row x 4 col), BM=64.
// =====================================================================
__global__ __launch_bounds__(512)
void pool_attn_mfma_kernel(const float* __restrict__ x, const unsigned short* __restrict__ WaT,
                           const float* __restrict__ ba, float* __restrict__ attn)
{
    __shared__ unsigned short As[64 * DIMC];   // 24 KB
    __shared__ float Cs[16][489];              // 31.3 KB chunk
    __shared__ float ba_s[NATT];

    const int t  = threadIdx.x;
    const int l  = t & 63;
    const int w  = t >> 6;
    const int wr = w >> 2;          // 0..1
    const int wc = w & 3;           // 0..3
    const int by = blockIdx.x;      // 0..195

    if (t < NATT) ba_s[t] = ba[t] * SCALE_A;

    // ---- stage pooled A tile: 64 pooled rows x 192 ch, fp32->bf16 swizzled ----
#pragma unroll
    for (int i = 0; i < 6; ++i) {
        int f   = i * 2048 + t * 4;
        int row = f / DIMC;
        int k   = f - row * DIMC;
        int m   = by * 64 + row;
        int b   = m / NPIX;
        int r   = m - b * NPIX;
        int hh  = r / WPOOL;
        int ww  = r - hh * WPOOL;
        const float* xp = x + (((size_t)(b * NH + hh * 2)) * NWW + ww * 2) * DIMC + k;
        float4 v0 = *(const float4*)(xp);
        float4 v1 = *(const float4*)(xp + DIMC);
        float4 v2 = *(const float4*)(xp + (size_t)NWW * DIMC);
        float4 v3 = *(const float4*)(xp + (size_t)NWW * DIMC + DIMC);
        ushort4 u;
        u.x = f2bf(0.25f * (v0.x + v1.x + v2.x + v3.x));
        u.y = f2bf(0.25f * (v0.y + v1.y + v2.y + v3.y));
        u.z = f2bf(0.25f * (v0.z + v1.z + v2.z + v3.z));
        u.w = f2bf(0.25f * (v0.w + v1.w + v2.w + v3.w));
        int off = (row * 384 + k * 2) ^ ((row & 7) << 4);
        *(ushort4*)((char*)As + off) = u;
    }
    __syncthreads();

    f32x4 acc[2][8];
#pragma unroll
    for (int mi = 0; mi < 2; ++mi)
#pragma unroll
        for (int ni = 0; ni < 8; ++ni) acc[mi][ni] = (f32x4)0.f;

    const int arow0 = wr * 32 + (l & 15);
    const int kb    = (l >> 4) << 4;

#pragma unroll
    for (int ks = 0; ks < 6; ++ks) {
        bf16x8 a[2], b[8];
#pragma unroll
        for (int mi = 0; mi < 2; ++mi) {
            int row = arow0 + mi * 16;
            int off = (row * 384 + ks * 64 + kb) ^ ((row & 7) << 4);
            a[mi] = *(const bf16x8*)((const char*)As + off);
        }
#pragma unroll
        for (int ni = 0; ni < 8; ++ni) {
            int n = wc * 128 + ni * 16 + (l & 15);
            b[ni] = *(const bf16x8*)(WaT + (size_t)n * DIMC + ks * 32 + ((l >> 4) << 3));
        }
#pragma unroll
        for (int mi = 0; mi < 2; ++mi)
#pragma unroll
            for (int ni = 0; ni < 8; ++ni)
                acc[mi][ni] = __builtin_amdgcn_mfma_f32_16x16x32_bf16(
                    a[mi], b[ni], acc[mi][ni], 0, 0, 0);
    }

    // ---- fused bias + softmax, 16-row chunks ----
#pragma unroll
    for (int r0 = 0; r0 < 64; r0 += 16) {
        const int mi = (r0 >> 4) & 1;
        if (wr == (r0 >> 5)) {
#pragma unroll
            for (int ni = 0; ni < 8; ++ni) {
                int col = wc * 128 + ni * 16 + (l & 15);
                if (col < NATT) {
#pragma unroll
                    for (int r = 0; r < 4; ++r)
                        Cs[((l >> 4) << 2) + r][col] =
                            (mi == 0 ? acc[0][ni][r] : acc[1][ni][r]) + ba_s[col];
                }
            }
        }
        __syncthreads();
        for (int g = t; g < 864; g += 512) {
            int lr = g / 54;
            int gc = (g - lr * 54) * 9;
            const float* ap = &Cs[lr][gc];
            float mx = ap[0];
#pragma unroll
            for (int q = 1; q < 9; ++q) mx = fmaxf(mx, ap[q]);
            float e[9];
            float sum = 0.f;
#pragma unroll
            for (int q = 0; q < 9; ++q) { e[q] = __expf(ap[q] - mx); sum += e[q]; }
            float inv = 1.f / sum;
            int m = by * 64 + r0 + lr;
            float* dst = attn + (size_t)m * NATT + gc;
#pragma unroll
            for (int q = 0; q < 9; ++q) dst[q] = e[q] * inv;
        }
        __syncthreads();
    }
}

// =====================================================================
// Gather: static-batched loads, parity-specialized via block-uniform
// branch. Block = 192 thr = 2 pixels (qc=wq, wq+28; same parity) x 96
// float2-channel threads. vp/y are bf16.
// =====================================================================
template<int NI, int NJ>
static __device__ __forceinline__ void gather_body(
    int b, int p, int qc, int head, int c,
    const float* __restrict__ attn, const unsigned short* __restrict__ vp,
    unsigned short* __restrict__ y)
{
    const int pr = p >> 1;
    const int qr = qc >> 1;

    float accx = 0.f, accy = 0.f;

#pragma unroll
    for (int wi = 0; wi < NI; ++wi) {
        const int  hh  = (NI == 1) ? pr : (wi == 0 ? pr : pr + 1);
        const bool hv  = (NI == 1) || (wi == 0) || (pr + 1 < HPOOL);
        const int  hhs = hv ? hh : (HPOOL - 1);
        const int  iof = (NI == 1) ? 1 : (wi == 0 ? 2 : 0);
#pragma unroll
        for (int wj = 0; wj < NJ; ++wj) {
            const int  ww  = (NJ == 1) ? qr : (wj == 0 ? qr : qr + 1);
            const bool wv  = (NJ == 1) || (wj == 0) || (qr + 1 < WPOOL);
            const int  wws = wv ? ww : (WPOOL - 1);
            const bool ok  = hv && wv;
            const int  jof = (NJ == 1) ? 1 : (wj == 0 ? 2 : 0);

            const float* ap = attn +
                ((size_t)(b * NPIX + hhs * WPOOL + wws) * NATT + head * 81 + (iof * 3 + jof) * 9);
            float a[9];
#pragma unroll
            for (int k = 0; k < 9; ++k) a[k] = ok ? ap[k] : 0.f;

            const unsigned short* vb = vp +
                (((size_t)(b * VH + 2 * hhs)) * VW + 2 * wws) * DIMC + c;
            ushort2 v[9];
#pragma unroll
            for (int qi = 0; qi < 3; ++qi)
#pragma unroll
                for (int qj = 0; qj < 3; ++qj)
                    v[qi * 3 + qj] = *(const ushort2*)(vb + ((size_t)qi * VW + qj) * DIMC);

#pragma unroll
            for (int k = 0; k < 9; ++k) {
                accx = fmaf(a[k], bf2f(v[k].x), accx);
                accy = fmaf(a[k], bf2f(v[k].y), accy);
            }
        }
    }
    size_t pix = (size_t)b * (NH * NWW) + (size_t)p * NWW + qc;
    ushort2 r;
    r.x = f2bf(accx);
    r.y = f2bf(accy);
    *(ushort2*)(y + pix * DIMC + c) = r;
}

__global__ __launch_bounds__(192)
void gather_kernel(const float* __restrict__ attn, const unsigned short* __restrict__ vp,
                   unsigned short* __restrict__ y)
{
    const int t    = threadIdx.x;
    const int pl   = t / 96;
    const int c2   = t - pl * 96;
    const int c    = c2 * 2;
    const int head = c2 >> 4;
    const int wq   = blockIdx.x;           // 0..27
    const int p    = blockIdx.y;           // 0..55
    const int b    = blockIdx.z;
    const int qc   = wq + pl * 28;

    if (p & 1) {
        if (wq & 1) gather_body<2, 2>(b, p, qc, head, c, attn, vp, y);
        else        gather_body<2, 1>(b, p, qc, head, c, attn, vp, y);
    } else {
        if (wq & 1) gather_body<1, 2>(b, p, qc, head, c, attn, vp, y);
        else        gather_body<1, 1>(b, p, qc, head, c, attn, vp, y);
    }
}

// =====================================================================
extern "C" void kernel_launch(void* const* d_in, const int* in_sizes, int n_in,
                              void* d_out, int out_size, void* d_ws, size_t ws_size,
                              hipStream_t stream)
{
    const float* x  = (const float*)d_in[0];
    const float* Wv = (const float*)d_in[1];
    const float* Wa = (const float*)d_in[2];
    const float* ba = (const float*)d_in[3];
    const float* Wp = (const float*)d_in[4];
    const float* bp = (const float*)d_in[5];
    float* out = (float*)d_out;

    const size_t vp_elems   = (size_t)NB * VH * VW * DIMC;   // 10,334,208 (bf16)
    const size_t attn_elems = (size_t)MPOOL * NATT;          //  6,096,384 (f32)
    const size_t y_elems    = (size_t)MROWS * DIMC;          //  9,633,792 (bf16)

    unsigned short* vp   = (unsigned short*)d_ws;
    float*          attn = (float*)(vp + vp_elems);
    unsigned short* y    = (unsigned short*)(attn + attn_elems);
    unsigned short* WTv  = y + y_elems;
    unsigned short* WTp  = WTv + 36864;
    unsigned short* WaT  = WTp + 36864;                      // 512*192

    vp_border_zero_kernel<<<1369, 256, 0, stream>>>((unsigned int*)vp);
    wt_convert_kernel<<<672, 256, 0, stream>>>(Wv, Wp, Wa, WTv, WTp, WaT);

    // v = x @ Wv -> padded vp (bf16)
    mfma_gemm_kernel<0><<<MROWS / 64, 256, 0, stream>>>(x, WTv, nullptr, vp);

    // pooled @ Wa + ba, softmax -> attn
    pool_attn_mfma_kernel<<<MPOOL / 64, 512, 0, stream>>>(x, WaT, ba, attn);

    // einsum + fold
    gather_kernel<<<dim3(28, 56, 16), 192, 0, stream>>>(attn, vp, y);

    // out = y @ Wp + bp
    mfma_gemm_kernel<1><<<MROWS / 64, 256, 0, stream>>>(y, WTp, bp, out);
}

// Round 5
// 123.170 us; speedup vs baseline: 1.8300x; 1.0577x over previous
//
#include <hip/hip_runtime.h>
#include <cstdint>
#include <cstddef>

#define DIMC    192
#define NHEADS  6
#define NATT    486
#define NB      16
#define NH      56
#define NWW     56
#define HPOOL   28
#define WPOOL   28
#define NPIX    784
#define VH      58
#define VW      58
#define MROWS   (NB*NH*NWW)      // 50176
#define MPOOL   (NB*NPIX)        // 12544
#define SCALE_A 0.17677669529663687f

using bf16x8 = __attribute__((ext_vector_type(8))) short;
using f32x4  = __attribute__((ext_vector_type(4))) float;

static __device__ __forceinline__ unsigned short f2bf(float f) {
    unsigned int u = __float_as_uint(f);
    unsigned int r = (u + 0x7fffu + ((u >> 16) & 1u)) >> 16;   // RNE
    return (unsigned short)r;
}
static __device__ __forceinline__ float bf2f(unsigned short u) {
    return __uint_as_float((unsigned int)u << 16);
}

// =====================================================================
// Weight prep: WTv/WTp[n][k] = bf16(W[k][n]); WaT[512][192] = bf16(Wa[k][n]*SCALE)
// =====================================================================
__global__ __launch_bounds__(256)
void wt_convert_kernel(const float* __restrict__ Wv, const float* __restrict__ Wp,
                       const float* __restrict__ Wa,
                       unsigned short* __restrict__ WTv, unsigned short* __restrict__ WTp,
                       unsigned short* __restrict__ WaT)
{
    int idx = blockIdx.x * 256 + threadIdx.x;        // 0..172031
    if (idx < 73728) {
        int sel = idx / 36864;
        int r   = idx - sel * 36864;
        int n   = r / DIMC;
        int k   = r - n * DIMC;
        const float* W = sel ? Wp : Wv;
        unsigned short* WT = sel ? WTp : WTv;
        WT[r] = f2bf(W[k * DIMC + n]);
    } else {
        int r = idx - 73728;                          // 0..98303
        int n = r / DIMC;
        int k = r - n * DIMC;
        WaT[r] = (n < NATT) ? f2bf(Wa[(size_t)k * NATT + n] * SCALE_A) : (unsigned short)0;
    }
}

// =====================================================================
// Zero the 1-pixel border of vp (bf16), as uint writes
// =====================================================================
__global__ __launch_bounds__(256)
void vp_border_zero_kernel(unsigned int* __restrict__ vpu)
{
    int idx = blockIdx.x * 256 + threadIdx.x;
    if (idx >= 350208) return;
    int cu   = idx % 96;
    int rest = idx / 96;
    int b    = rest / 228;
    int p    = rest - b * 228;
    int hi, wi;
    if (p < 58)       { hi = 0;  wi = p; }
    else if (p < 116) { hi = 57; wi = p - 58; }
    else { int q = p - 116; hi = 1 + (q >> 1); wi = (q & 1) * 57; }
    vpu[(((size_t)b * VH + hi) * VW + wi) * 96 + cu] = 0u;
}

// =====================================================================
// MFMA GEMM, BM=64, BN=192 (full), 4 waves (2x2).
// MODE 0: A fp32 (x), C bf16 scattered into padded vp
// MODE 1: A bf16 (y), C fp32 + bias -> out
// =====================================================================
template<int MODE>
__global__ __launch_bounds__(256)
void mfma_gemm_kernel(const void* __restrict__ Av, const unsigned short* __restrict__ WT,
                      const float* __restrict__ bias, void* __restrict__ Cv)
{
    __shared__ unsigned short As[64 * DIMC];   // 24 KB swizzled bf16

    const int t  = threadIdx.x;
    const int l  = t & 63;
    const int w  = t >> 6;
    const int wr = w >> 1;
    const int wc = w & 1;
    const int by = blockIdx.x;

    if (MODE == 0) {
        const float* Ab = (const float*)Av + (size_t)by * 64 * DIMC;
#pragma unroll
        for (int i = 0; i < 12; ++i) {
            int f = i * 1024 + t * 4;
            float4 v = *(const float4*)(Ab + f);
            int row = f / DIMC;
            int k   = f - row * DIMC;
            ushort4 u;
            u.x = f2bf(v.x); u.y = f2bf(v.y); u.z = f2bf(v.z); u.w = f2bf(v.w);
            int off = (row * 384 + k * 2) ^ ((row & 7) << 4);
            *(ushort4*)((char*)As + off) = u;
        }
    } else {
        const unsigned short* Ab = (const unsigned short*)Av + (size_t)by * 64 * DIMC;
#pragma unroll
        for (int i = 0; i < 6; ++i) {
            int f = i * 2048 + t * 8;
            bf16x8 v = *(const bf16x8*)(Ab + f);
            int row = f / DIMC;
            int k   = f - row * DIMC;
            int off = (row * 384 + k * 2) ^ ((row & 7) << 4);
            *(bf16x8*)((char*)As + off) = v;
        }
    }
    __syncthreads();

    f32x4 acc[2][6];
#pragma unroll
    for (int mi = 0; mi < 2; ++mi)
#pragma unroll
        for (int ni = 0; ni < 6; ++ni) acc[mi][ni] = (f32x4)0.f;

    const int arow0 = wr * 32 + (l & 15);
    const int kb    = (l >> 4) << 4;

#pragma unroll
    for (int ks = 0; ks < 6; ++ks) {
        bf16x8 a[2], b[6];
#pragma unroll
        for (int mi = 0; mi < 2; ++mi) {
            int row = arow0 + mi * 16;
            int off = (row * 384 + ks * 64 + kb) ^ ((row & 7) << 4);
            a[mi] = *(const bf16x8*)((const char*)As + off);
        }
#pragma unroll
        for (int ni = 0; ni < 6; ++ni) {
            int n = wc * 96 + ni * 16 + (l & 15);
            b[ni] = *(const bf16x8*)(WT + (size_t)n * DIMC + ks * 32 + ((l >> 4) << 3));
        }
#pragma unroll
        for (int mi = 0; mi < 2; ++mi)
#pragma unroll
            for (int ni = 0; ni < 6; ++ni)
                acc[mi][ni] = __builtin_amdgcn_mfma_f32_16x16x32_bf16(
                    a[mi], b[ni], acc[mi][ni], 0, 0, 0);
    }

#pragma unroll
    for (int mi = 0; mi < 2; ++mi) {
#pragma unroll
        for (int r = 0; r < 4; ++r) {
            int m = by * 64 + wr * 32 + mi * 16 + ((l >> 4) << 2) + r;
            if (MODE == 1) {
                float* dst = (float*)Cv + (size_t)m * DIMC;
#pragma unroll
                for (int ni = 0; ni < 6; ++ni) {
                    int col = wc * 96 + ni * 16 + (l & 15);
                    dst[col] = acc[mi][ni][r] + bias[col];
                }
            } else {
                int bb = m / (NH * NWW);
                int rr = m - bb * (NH * NWW);
                int hi = rr / NWW;
                int wi = rr - hi * NWW;
                unsigned short* dst = (unsigned short*)Cv +
                    (((size_t)bb * VH + hi + 1) * VW + (wi + 1)) * DIMC;
#pragma unroll
                for (int ni = 0; ni < 6; ++ni) {
                    int col = wc * 96 + ni * 16 + (l & 15);
                    dst[col] = f2bf(acc[mi][ni][r]);
                }
            }
        }
    }
}

// =====================================================================
// Fused pool + MFMA GEMM (M=12544, N=512pad, K=192) + softmax -> attn f32
// =====================================================================
__global__ __launch_bounds__(512)
void pool_attn_mfma_kernel(const float* __restrict__ x, const unsigned short* __restrict__ WaT,
                           const float* __restrict__ ba, float* __restrict__ attn)
{
    __shared__ unsigned short As[64 * DIMC];   // 24 KB
    __shared__ float Cs[16][489];              // 31.3 KB chunk
    __shared__ float ba_s[NATT];

    const int t  = threadIdx.x;
    const int l  = t & 63;
    const int w  = t >> 6;
    const int wr = w >> 2;
    const int wc = w & 3;
    const int by = blockIdx.x;

    if (t < NATT) ba_s[t] = ba[t] * SCALE_A;

#pragma unroll
    for (int i = 0; i < 6; ++i) {
        int f   = i * 2048 + t * 4;
        int row = f / DIMC;
        int k   = f - row * DIMC;
        int m   = by * 64 + row;
        int b   = m / NPIX;
        int r   = m - b * NPIX;
        int hh  = r / WPOOL;
        int ww  = r - hh * WPOOL;
        const float* xp = x + (((size_t)(b * NH + hh * 2)) * NWW + ww * 2) * DIMC + k;
        float4 v0 = *(const float4*)(xp);
        float4 v1 = *(const float4*)(xp + DIMC);
        float4 v2 = *(const float4*)(xp + (size_t)NWW * DIMC);
        float4 v3 = *(const float4*)(xp + (size_t)NWW * DIMC + DIMC);
        ushort4 u;
        u.x = f2bf(0.25f * (v0.x + v1.x + v2.x + v3.x));
        u.y = f2bf(0.25f * (v0.y + v1.y + v2.y + v3.y));
        u.z = f2bf(0.25f * (v0.z + v1.z + v2.z + v3.z));
        u.w = f2bf(0.25f * (v0.w + v1.w + v2.w + v3.w));
        int off = (row * 384 + k * 2) ^ ((row & 7) << 4);
        *(ushort4*)((char*)As + off) = u;
    }
    __syncthreads();

    f32x4 acc[2][8];
#pragma unroll
    for (int mi = 0; mi < 2; ++mi)
#pragma unroll
        for (int ni = 0; ni < 8; ++ni) acc[mi][ni] = (f32x4)0.f;

    const int arow0 = wr * 32 + (l & 15);
    const int kb    = (l >> 4) << 4;

#pragma unroll
    for (int ks = 0; ks < 6; ++ks) {
        bf16x8 a[2], b[8];
#pragma unroll
        for (int mi = 0; mi < 2; ++mi) {
            int row = arow0 + mi * 16;
            int off = (row * 384 + ks * 64 + kb) ^ ((row & 7) << 4);
            a[mi] = *(const bf16x8*)((const char*)As + off);
        }
#pragma unroll
        for (int ni = 0; ni < 8; ++ni) {
            int n = wc * 128 + ni * 16 + (l & 15);
            b[ni] = *(const bf16x8*)(WaT + (size_t)n * DIMC + ks * 32 + ((l >> 4) << 3));
        }
#pragma unroll
        for (int mi = 0; mi < 2; ++mi)
#pragma unroll
            for (int ni = 0; ni < 8; ++ni)
                acc[mi][ni] = __builtin_amdgcn_mfma_f32_16x16x32_bf16(
                    a[mi], b[ni], acc[mi][ni], 0, 0, 0);
    }

#pragma unroll
    for (int r0 = 0; r0 < 64; r0 += 16) {
        const int mi = (r0 >> 4) & 1;
        if (wr == (r0 >> 5)) {
#pragma unroll
            for (int ni = 0; ni < 8; ++ni) {
                int col = wc * 128 + ni * 16 + (l & 15);
                if (col < NATT) {
#pragma unroll
                    for (int r = 0; r < 4; ++r)
                        Cs[((l >> 4) << 2) + r][col] =
                            (mi == 0 ? acc[0][ni][r] : acc[1][ni][r]) + ba_s[col];
                }
            }
        }
        __syncthreads();
        for (int g = t; g < 864; g += 512) {
            int lr = g / 54;
            int gc = (g - lr * 54) * 9;
            const float* ap = &Cs[lr][gc];
            float mx = ap[0];
#pragma unroll
            for (int q = 1; q < 9; ++q) mx = fmaxf(mx, ap[q]);
            float e[9];
            float sum = 0.f;
#pragma unroll
            for (int q = 0; q < 9; ++q) { e[q] = __expf(ap[q] - mx); sum += e[q]; }
            float inv = 1.f / sum;
            int m = by * 64 + r0 + lr;
            float* dst = attn + (size_t)m * NATT + gc;
#pragma unroll
            for (int q = 0; q < 9; ++q) dst[q] = e[q] * inv;
        }
        __syncthreads();
    }
}

// =====================================================================
// Gather with bijective XCD swizzle: 1D grid 25088 blocks, block w goes
// to XCD w%8 (HW round-robin); remap so XCD i owns batches 2i,2i+1 and
// sweeps (p, wq) row-major -> vp (1.3 MB/batch bf16) stays L2-hot.
// =====================================================================
template<int NI, int NJ>
static __device__ __forceinline__ void gather_body(
    int b, int p, int qc, int head, int c,
    const float* __restrict__ attn, const unsigned short* __restrict__ vp,
    unsigned short* __restrict__ y)
{
    const int pr = p >> 1;
    const int qr = qc >> 1;

    float accx = 0.f, accy = 0.f;

#pragma unroll
    for (int wi = 0; wi < NI; ++wi) {
        const int  hh  = (NI == 1) ? pr : (wi == 0 ? pr : pr + 1);
        const bool hv  = (NI == 1) || (wi == 0) || (pr + 1 < HPOOL);
        const int  hhs = hv ? hh : (HPOOL - 1);
        const int  iof = (NI == 1) ? 1 : (wi == 0 ? 2 : 0);
#pragma unroll
        for (int wj = 0; wj < NJ; ++wj) {
            const int  ww  = (NJ == 1) ? qr : (wj == 0 ? qr : qr + 1);
            const bool wv  = (NJ == 1) || (wj == 0) || (qr + 1 < WPOOL);
            const int  wws = wv ? ww : (WPOOL - 1);
            const bool ok  = hv && wv;
            const int  jof = (NJ == 1) ? 1 : (wj == 0 ? 2 : 0);

            const float* ap = attn +
                ((size_t)(b * NPIX + hhs * WPOOL + wws) * NATT + head * 81 + (iof * 3 + jof) * 9);
            float a[9];
#pragma unroll
            for (int k = 0; k < 9; ++k) a[k] = ok ? ap[k] : 0.f;

            const unsigned short* vb = vp +
                (((size_t)(b * VH + 2 * hhs)) * VW + 2 * wws) * DIMC + c;
            ushort2 v[9];
#pragma unroll
            for (int qi = 0; qi < 3; ++qi)
#pragma unroll
                for (int qj = 0; qj < 3; ++qj)
                    v[qi * 3 + qj] = *(const ushort2*)(vb + ((size_t)qi * VW + qj) * DIMC);

#pragma unroll
            for (int k = 0; k < 9; ++k) {
                accx = fmaf(a[k], bf2f(v[k].x), accx);
                accy = fmaf(a[k], bf2f(v[k].y), accy);
            }
        }
    }
    size_t pix = (size_t)b * (NH * NWW) + (size_t)p * NWW + qc;
    ushort2 r;
    r.x = f2bf(accx);
    r.y = f2bf(accy);
    *(ushort2*)(y + pix * DIMC + c) = r;
}

__global__ __launch_bounds__(192)
void gather_kernel(const float* __restrict__ attn, const unsigned short* __restrict__ vp,
                   unsigned short* __restrict__ y)
{
    const int t    = threadIdx.x;
    const int pl   = t / 96;
    const int c2   = t - pl * 96;
    const int c    = c2 * 2;
    const int head = c2 >> 4;

    // bijective XCD swizzle: 25088 = 8 * 3136; XCD (flat&7) owns a
    // contiguous wgid chunk = 2 whole batches, swept (p, wq) row-major
    const int flat = blockIdx.x;
    const int wgid = (flat & 7) * 3136 + (flat >> 3);
    const int b    = wgid / 1568;
    const int rr   = wgid - b * 1568;
    const int p    = rr / 28;
    const int wq   = rr - p * 28;
    const int qc   = wq + pl * 28;

    if (p & 1) {
        if (wq & 1) gather_body<2, 2>(b, p, qc, head, c, attn, vp, y);
        else        gather_body<2, 1>(b, p, qc, head, c, attn, vp, y);
    } else {
        if (wq & 1) gather_body<1, 2>(b, p, qc, head, c, attn, vp, y);
        else        gather_body<1, 1>(b, p, qc, head, c, attn, vp, y);
    }
}

// =====================================================================
extern "C" void kernel_launch(void* const* d_in, const int* in_sizes, int n_in,
                              void* d_out, int out_size, void* d_ws, size_t ws_size,
                              hipStream_t stream)
{
    const float* x  = (const float*)d_in[0];
    const float* Wv = (const float*)d_in[1];
    const float* Wa = (const float*)d_in[2];
    const float* ba = (const float*)d_in[3];
    const float* Wp = (const float*)d_in[4];
    const float* bp = (const float*)d_in[5];
    float* out = (float*)d_out;

    const size_t vp_elems   = (size_t)NB * VH * VW * DIMC;   // bf16
    const size_t attn_elems = (size_t)MPOOL * NATT;          // f32
    const size_t y_elems    = (size_t)MROWS * DIMC;          // bf16

    unsigned short* vp   = (unsigned short*)d_ws;
    float*          attn = (float*)(vp + vp_elems);
    unsigned short* y    = (unsigned short*)(attn + attn_elems);
    unsigned short* WTv  = y + y_elems;
    unsigned short* WTp  = WTv + 36864;
    unsigned short* WaT  = WTp + 36864;

    vp_border_zero_kernel<<<1369, 256, 0, stream>>>((unsigned int*)vp);
    wt_convert_kernel<<<672, 256, 0, stream>>>(Wv, Wp, Wa, WTv, WTp, WaT);

    mfma_gemm_kernel<0><<<MROWS / 64, 256, 0, stream>>>(x, WTv, nullptr, vp);
    pool_attn_mfma_kernel<<<MPOOL / 64, 512, 0, stream>>>(x, WaT, ba, attn);

    gather_kernel<<<25088, 192, 0, stream>>>(attn, vp, y);

    mfma_gemm_kernel<1><<<MROWS / 64, 256, 0, stream>>>(y, WTp, bp, out);
}